// Round 8
// baseline (1433.374 us; speedup 1.0000x reference)
//
#include <hip/hip_runtime.h>

#define TOTAL 524288
#define NSEG  16384

typedef float f4 __attribute__((ext_vector_type(4)));

// ---------------------------------------------------------------------------
// Kernel 1: phi MLP (8->64 relu, 64->64 relu, 64->64) per row, then
// wave-level segmented suffix-sum (ids sorted) + atomics from run heads.
// h-state held as f4 vectors with compile-time-constant indices ONLY
// (rule #20: runtime-indexed arrays go to scratch). launch_bounds(256,1)
// lifts the VGPR cap to 512 so the unrolled body cannot spill.
// ---------------------------------------------------------------------------
__global__ __launch_bounds__(256, 1) void phi_pool_kernel(
    const float* __restrict__ x,      // [TOTAL, 8]
    const int*   __restrict__ seg,    // [TOTAL] sorted
    const float* __restrict__ W1, const float* __restrict__ b1,   // [8,64],[64]
    const float* __restrict__ W2, const float* __restrict__ b2,   // [64,64],[64]
    const float* __restrict__ W3, const float* __restrict__ b3,   // [64,64],[64]
    float* __restrict__ pooled)       // [NSEG, 64] (pre-zeroed)
{
    const int r = blockIdx.x * 256 + threadIdx.x;

    // issue VMEM loads (segment id + row) before the FMA body
    const int s = seg[r];
    const f4* xp = reinterpret_cast<const f4*>(x + (size_t)r * 8);
    const f4 x0 = xp[0], x1 = xp[1];

    const f4* W1v = reinterpret_cast<const f4*>(W1);  // [8][16] f4
    const f4* b1v = reinterpret_cast<const f4*>(b1);
    const f4* W2v = reinterpret_cast<const f4*>(W2);  // [64][16] f4
    const f4* b2v = reinterpret_cast<const f4*>(b2);
    const f4* W3v = reinterpret_cast<const f4*>(W3);  // [64][16] f4
    const f4* b3v = reinterpret_cast<const f4*>(b3);

    // ---- layer 1: 8 -> 64, relu ----
    f4 h1[16];
#pragma unroll
    for (int j = 0; j < 16; ++j) h1[j] = b1v[j];
#pragma unroll
    for (int k = 0; k < 8; ++k) {
        const float a = (k < 4) ? x0[k] : x1[k - 4];   // k is compile-time
#pragma unroll
        for (int j = 0; j < 16; ++j) h1[j] += W1v[k * 16 + j] * a;
    }
#pragma unroll
    for (int j = 0; j < 16; ++j) {
#pragma unroll
        for (int e = 0; e < 4; ++e) h1[j][e] = fmaxf(h1[j][e], 0.0f);
    }

    // ---- layer 2: 64 -> 64, relu ----
    f4 h2[16];
#pragma unroll
    for (int j = 0; j < 16; ++j) h2[j] = b2v[j];
#pragma unroll
    for (int k = 0; k < 64; ++k) {
        const float a = h1[k >> 2][k & 3];             // compile-time indices
#pragma unroll
        for (int j = 0; j < 16; ++j) h2[j] += W2v[k * 16 + j] * a;
    }
#pragma unroll
    for (int j = 0; j < 16; ++j) {
#pragma unroll
        for (int e = 0; e < 4; ++e) h2[j][e] = fmaxf(h2[j][e], 0.0f);
    }

    // ---- layer 3: 64 -> 64 (no relu) ----
    f4 h3[16];
#pragma unroll
    for (int j = 0; j < 16; ++j) h3[j] = b3v[j];
#pragma unroll
    for (int k = 0; k < 64; ++k) {
        const float a = h2[k >> 2][k & 3];
#pragma unroll
        for (int j = 0; j < 16; ++j) h3[j] += W3v[k * 16 + j] * a;
    }

    // ---- wave-level segmented suffix sum over sorted ids ----
    const int lane = threadIdx.x & 63;

    // precompute per-distance run-membership masks once (not per feature)
    bool ok0, ok1, ok2, ok3, ok4, ok5;
    {
        const int s1  = __shfl_down(s, 1);
        const int s2  = __shfl_down(s, 2);
        const int s4  = __shfl_down(s, 4);
        const int s8  = __shfl_down(s, 8);
        const int s16 = __shfl_down(s, 16);
        const int s32 = __shfl_down(s, 32);
        ok0 = (lane + 1  < 64) && (s1  == s);
        ok1 = (lane + 2  < 64) && (s2  == s);
        ok2 = (lane + 4  < 64) && (s4  == s);
        ok3 = (lane + 8  < 64) && (s8  == s);
        ok4 = (lane + 16 < 64) && (s16 == s);
        ok5 = (lane + 32 < 64) && (s32 == s);
    }
    const int  sprev = __shfl_up(s, 1);
    const bool head  = (lane == 0) || (sprev != s);
    float* p = pooled + (size_t)s * 64;

    // scan one f4 chunk at a time: minimal extra register pressure
#pragma unroll
    for (int j = 0; j < 16; ++j) {
        f4 v = h3[j];
#pragma unroll
        for (int t = 0; t < 6; ++t) {
            const int d = 1 << t;
            f4 o;
#pragma unroll
            for (int e = 0; e < 4; ++e) o[e] = __shfl_down(v[e], d);
            const bool ok = (t == 0) ? ok0 : (t == 1) ? ok1 : (t == 2) ? ok2
                          : (t == 3) ? ok3 : (t == 4) ? ok4 : ok5;
            if (ok) v += o;    // exec-masked add
        }
        if (head) {
#pragma unroll
            for (int e = 0; e < 4; ++e) atomicAdd(p + j * 4 + e, v[e]);
        }
    }
}

// ---------------------------------------------------------------------------
// Kernel 2: rho MLP (64->64 relu, 64->64 relu, 64->4) per pooled row.
// 64-thread blocks, 256 blocks -> covers all 256 CUs (was 64 blocks = 25%).
// Same vector-register structure as phi.
// ---------------------------------------------------------------------------
__global__ __launch_bounds__(64, 1) void rho_kernel(
    const float* __restrict__ pooled,  // [NSEG, 64]
    const float* __restrict__ W1, const float* __restrict__ b1,   // [64,64],[64]
    const float* __restrict__ W2, const float* __restrict__ b2,   // [64,64],[64]
    const float* __restrict__ W3, const float* __restrict__ b3,   // [64,4],[4]
    float* __restrict__ out)           // [NSEG, 4]
{
    const int r = blockIdx.x * 64 + threadIdx.x;

    const f4* W1v = reinterpret_cast<const f4*>(W1);
    const f4* b1v = reinterpret_cast<const f4*>(b1);
    const f4* W2v = reinterpret_cast<const f4*>(W2);
    const f4* b2v = reinterpret_cast<const f4*>(b2);
    const f4* W3v = reinterpret_cast<const f4*>(W3);  // [64][1] f4
    const f4* b3v = reinterpret_cast<const f4*>(b3);

    f4 h0[16];
    const f4* pp = reinterpret_cast<const f4*>(pooled + (size_t)r * 64);
#pragma unroll
    for (int j = 0; j < 16; ++j) h0[j] = pp[j];

    f4 h1[16];
#pragma unroll
    for (int j = 0; j < 16; ++j) h1[j] = b1v[j];
#pragma unroll
    for (int k = 0; k < 64; ++k) {
        const float a = h0[k >> 2][k & 3];
#pragma unroll
        for (int j = 0; j < 16; ++j) h1[j] += W1v[k * 16 + j] * a;
    }
#pragma unroll
    for (int j = 0; j < 16; ++j) {
#pragma unroll
        for (int e = 0; e < 4; ++e) h1[j][e] = fmaxf(h1[j][e], 0.0f);
    }

    f4 h2[16];
#pragma unroll
    for (int j = 0; j < 16; ++j) h2[j] = b2v[j];
#pragma unroll
    for (int k = 0; k < 64; ++k) {
        const float a = h1[k >> 2][k & 3];
#pragma unroll
        for (int j = 0; j < 16; ++j) h2[j] += W2v[k * 16 + j] * a;
    }
#pragma unroll
    for (int j = 0; j < 16; ++j) {
#pragma unroll
        for (int e = 0; e < 4; ++e) h2[j][e] = fmaxf(h2[j][e], 0.0f);
    }

    f4 o4 = b3v[0];
#pragma unroll
    for (int k = 0; k < 64; ++k) {
        const float a = h2[k >> 2][k & 3];
        o4 += W3v[k] * a;
    }

    f4* op = reinterpret_cast<f4*>(out + (size_t)r * 4);
    *op = o4;
}

extern "C" void kernel_launch(void* const* d_in, const int* in_sizes, int n_in,
                              void* d_out, int out_size, void* d_ws, size_t ws_size,
                              hipStream_t stream) {
    const float* neighbors = (const float*)d_in[0];
    const int*   seg       = (const int*)d_in[1];
    const float* phi_W1 = (const float*)d_in[2];
    const float* phi_b1 = (const float*)d_in[3];
    const float* phi_W2 = (const float*)d_in[4];
    const float* phi_b2 = (const float*)d_in[5];
    const float* phi_W3 = (const float*)d_in[6];
    const float* phi_b3 = (const float*)d_in[7];
    const float* rho_W1 = (const float*)d_in[8];
    const float* rho_b1 = (const float*)d_in[9];
    const float* rho_W2 = (const float*)d_in[10];
    const float* rho_b2 = (const float*)d_in[11];
    const float* rho_W3 = (const float*)d_in[12];
    const float* rho_b3 = (const float*)d_in[13];

    float* pooled = (float*)d_ws;                       // [NSEG, 64]
    float* outp   = (float*)d_out;                      // [NSEG, 4]

    // ws is re-poisoned to 0xAA before every launch -> must zero accumulator
    hipMemsetAsync(pooled, 0, (size_t)NSEG * 64 * sizeof(float), stream);

    phi_pool_kernel<<<TOTAL / 256, 256, 0, stream>>>(
        neighbors, seg, phi_W1, phi_b1, phi_W2, phi_b2, phi_W3, phi_b3, pooled);

    rho_kernel<<<NSEG / 64, 64, 0, stream>>>(
        pooled, rho_W1, rho_b1, rho_W2, rho_b2, rho_W3, rho_b3, outp);
}

// Round 10
// 995.926 us; speedup vs baseline: 1.4392x; 1.4392x over previous
//
#include <hip/hip_runtime.h>

#define TOTAL 524288
#define NSEG  16384

typedef float f4 __attribute__((ext_vector_type(4)));

// ---------------------------------------------------------------------------
// phi MLP (8->64 relu, 64->64 relu, 64->64) per row + sorted-segment wave
// suffix-scan + run-head atomics.
// h state: f4[16] (SROA-promotable, proven R8: VGPR=188).
// Weights: SCALAR float reads at wave-uniform compile-time indices
// (proven R7: s_load/SGPR path, 112 SGPR). Do NOT cast weights to vectors —
// that broke scalarization in R8 (per-lane dwordx4 of same addr, 4.7x slower).
// ---------------------------------------------------------------------------
__global__ __launch_bounds__(256, 2) void phi_pool_kernel(
    const float* __restrict__ x,      // [TOTAL, 8]
    const int*   __restrict__ seg,    // [TOTAL] sorted
    const float* __restrict__ W1, const float* __restrict__ b1,   // [8,64],[64]
    const float* __restrict__ W2, const float* __restrict__ b2,   // [64,64],[64]
    const float* __restrict__ W3, const float* __restrict__ b3,   // [64,64],[64]
    float* __restrict__ pooled)       // [NSEG, 64] (pre-zeroed)
{
    const int r = blockIdx.x * 256 + threadIdx.x;

    // issue per-lane VMEM loads (segment id + row) before the FMA body
    const int s = seg[r];
    const f4* xp = reinterpret_cast<const f4*>(x + (size_t)r * 8);
    const f4 x0 = xp[0], x1 = xp[1];

    // ---- layer 1: 8 -> 64, relu ----
    f4 h1[16];
#pragma unroll
    for (int j = 0; j < 16; ++j) {
#pragma unroll
        for (int e = 0; e < 4; ++e) h1[j][e] = b1[j * 4 + e];
    }
#pragma unroll
    for (int k = 0; k < 8; ++k) {
        const float a = (k < 4) ? x0[k] : x1[k - 4];   // k compile-time
#pragma unroll
        for (int j = 0; j < 16; ++j) {
#pragma unroll
            for (int e = 0; e < 4; ++e)
                h1[j][e] = fmaf(a, W1[k * 64 + j * 4 + e], h1[j][e]);
        }
    }
#pragma unroll
    for (int j = 0; j < 16; ++j) {
#pragma unroll
        for (int e = 0; e < 4; ++e) h1[j][e] = fmaxf(h1[j][e], 0.0f);
    }

    // ---- layer 2: 64 -> 64, relu ----
    f4 h2[16];
#pragma unroll
    for (int j = 0; j < 16; ++j) {
#pragma unroll
        for (int e = 0; e < 4; ++e) h2[j][e] = b2[j * 4 + e];
    }
#pragma unroll
    for (int k = 0; k < 64; ++k) {
        const float a = h1[k >> 2][k & 3];             // compile-time indices
#pragma unroll
        for (int j = 0; j < 16; ++j) {
#pragma unroll
            for (int e = 0; e < 4; ++e)
                h2[j][e] = fmaf(a, W2[k * 64 + j * 4 + e], h2[j][e]);
        }
    }
#pragma unroll
    for (int j = 0; j < 16; ++j) {
#pragma unroll
        for (int e = 0; e < 4; ++e) h2[j][e] = fmaxf(h2[j][e], 0.0f);
    }

    // ---- layer 3: 64 -> 64 (no relu) ----
    f4 h3[16];
#pragma unroll
    for (int j = 0; j < 16; ++j) {
#pragma unroll
        for (int e = 0; e < 4; ++e) h3[j][e] = b3[j * 4 + e];
    }
#pragma unroll
    for (int k = 0; k < 64; ++k) {
        const float a = h2[k >> 2][k & 3];
#pragma unroll
        for (int j = 0; j < 16; ++j) {
#pragma unroll
            for (int e = 0; e < 4; ++e)
                h3[j][e] = fmaf(a, W3[k * 64 + j * 4 + e], h3[j][e]);
        }
    }

    // ---- wave-level segmented suffix sum over sorted ids ----
    const int lane = threadIdx.x & 63;

    bool ok0, ok1, ok2, ok3, ok4, ok5;
    {
        const int s1  = __shfl_down(s, 1);
        const int s2  = __shfl_down(s, 2);
        const int s4  = __shfl_down(s, 4);
        const int s8  = __shfl_down(s, 8);
        const int s16 = __shfl_down(s, 16);
        const int s32 = __shfl_down(s, 32);
        ok0 = (lane + 1  < 64) && (s1  == s);
        ok1 = (lane + 2  < 64) && (s2  == s);
        ok2 = (lane + 4  < 64) && (s4  == s);
        ok3 = (lane + 8  < 64) && (s8  == s);
        ok4 = (lane + 16 < 64) && (s16 == s);
        ok5 = (lane + 32 < 64) && (s32 == s);
    }
    const int  sprev = __shfl_up(s, 1);
    const bool head  = (lane == 0) || (sprev != s);
    float* p = pooled + (size_t)s * 64;

    // scan one f4 chunk at a time: minimal extra register pressure
#pragma unroll
    for (int j = 0; j < 16; ++j) {
        f4 v = h3[j];
#pragma unroll
        for (int t = 0; t < 6; ++t) {
            const int d = 1 << t;
            f4 o;
#pragma unroll
            for (int e = 0; e < 4; ++e) o[e] = __shfl_down(v[e], d);
            const bool ok = (t == 0) ? ok0 : (t == 1) ? ok1 : (t == 2) ? ok2
                          : (t == 3) ? ok3 : (t == 4) ? ok4 : ok5;
            if (ok) v += o;    // exec-masked add
        }
        if (head) {
#pragma unroll
            for (int e = 0; e < 4; ++e) atomicAdd(p + j * 4 + e, v[e]);
        }
    }
}

// ---------------------------------------------------------------------------
// rho MLP (64->64 relu, 64->64 relu, 64->4) per pooled row.
// 256 blocks x 64 threads -> covers all CUs. Same f4-h / scalar-weight split.
// ---------------------------------------------------------------------------
__global__ __launch_bounds__(64, 2) void rho_kernel(
    const float* __restrict__ pooled,  // [NSEG, 64]
    const float* __restrict__ W1, const float* __restrict__ b1,   // [64,64],[64]
    const float* __restrict__ W2, const float* __restrict__ b2,   // [64,64],[64]
    const float* __restrict__ W3, const float* __restrict__ b3,   // [64,4],[4]
    float* __restrict__ out)           // [NSEG, 4]
{
    const int r = blockIdx.x * 64 + threadIdx.x;

    f4 h0[16];
    const f4* pp = reinterpret_cast<const f4*>(pooled + (size_t)r * 64);
#pragma unroll
    for (int j = 0; j < 16; ++j) h0[j] = pp[j];   // per-lane data: vector load OK

    f4 h1[16];
#pragma unroll
    for (int j = 0; j < 16; ++j) {
#pragma unroll
        for (int e = 0; e < 4; ++e) h1[j][e] = b1[j * 4 + e];
    }
#pragma unroll
    for (int k = 0; k < 64; ++k) {
        const float a = h0[k >> 2][k & 3];
#pragma unroll
        for (int j = 0; j < 16; ++j) {
#pragma unroll
            for (int e = 0; e < 4; ++e)
                h1[j][e] = fmaf(a, W1[k * 64 + j * 4 + e], h1[j][e]);
        }
    }
#pragma unroll
    for (int j = 0; j < 16; ++j) {
#pragma unroll
        for (int e = 0; e < 4; ++e) h1[j][e] = fmaxf(h1[j][e], 0.0f);
    }

    f4 h2[16];
#pragma unroll
    for (int j = 0; j < 16; ++j) {
#pragma unroll
        for (int e = 0; e < 4; ++e) h2[j][e] = b2[j * 4 + e];
    }
#pragma unroll
    for (int k = 0; k < 64; ++k) {
        const float a = h1[k >> 2][k & 3];
#pragma unroll
        for (int j = 0; j < 16; ++j) {
#pragma unroll
            for (int e = 0; e < 4; ++e)
                h2[j][e] = fmaf(a, W2[k * 64 + j * 4 + e], h2[j][e]);
        }
    }
#pragma unroll
    for (int j = 0; j < 16; ++j) {
#pragma unroll
        for (int e = 0; e < 4; ++e) h2[j][e] = fmaxf(h2[j][e], 0.0f);
    }

    f4 o4;
#pragma unroll
    for (int e = 0; e < 4; ++e) o4[e] = b3[e];
#pragma unroll
    for (int k = 0; k < 64; ++k) {
        const float a = h2[k >> 2][k & 3];
#pragma unroll
        for (int e = 0; e < 4; ++e)
            o4[e] = fmaf(a, W3[k * 4 + e], o4[e]);
    }

    f4* op = reinterpret_cast<f4*>(out + (size_t)r * 4);
    *op = o4;
}

extern "C" void kernel_launch(void* const* d_in, const int* in_sizes, int n_in,
                              void* d_out, int out_size, void* d_ws, size_t ws_size,
                              hipStream_t stream) {
    const float* neighbors = (const float*)d_in[0];
    const int*   seg       = (const int*)d_in[1];
    const float* phi_W1 = (const float*)d_in[2];
    const float* phi_b1 = (const float*)d_in[3];
    const float* phi_W2 = (const float*)d_in[4];
    const float* phi_b2 = (const float*)d_in[5];
    const float* phi_W3 = (const float*)d_in[6];
    const float* phi_b3 = (const float*)d_in[7];
    const float* rho_W1 = (const float*)d_in[8];
    const float* rho_b1 = (const float*)d_in[9];
    const float* rho_W2 = (const float*)d_in[10];
    const float* rho_b2 = (const float*)d_in[11];
    const float* rho_W3 = (const float*)d_in[12];
    const float* rho_b3 = (const float*)d_in[13];

    float* pooled = (float*)d_ws;                       // [NSEG, 64]
    float* outp   = (float*)d_out;                      // [NSEG, 4]

    // ws is re-poisoned to 0xAA before every launch -> must zero accumulator
    hipMemsetAsync(pooled, 0, (size_t)NSEG * 64 * sizeof(float), stream);

    phi_pool_kernel<<<TOTAL / 256, 256, 0, stream>>>(
        neighbors, seg, phi_W1, phi_b1, phi_W2, phi_b2, phi_W3, phi_b3, pooled);

    rho_kernel<<<NSEG / 64, 64, 0, stream>>>(
        pooled, rho_W1, rho_b1, rho_W2, rho_b2, rho_W3, rho_b3, outp);
}

// Round 13
// 737.491 us; speedup vs baseline: 1.9436x; 1.3504x over previous
//
#include <hip/hip_runtime.h>

#define TOTAL 524288
#define NSEG  16384

typedef float f4 __attribute__((ext_vector_type(4)));

// Whole-vector read-modify-write helpers: the alloca only ever sees full-f4
// loads/stores at constant indices -> cleanest pattern for PromoteAlloca.
#define INIT4(dst, B, base) { f4 _t; _t[0]=(B)[(base)+0]; _t[1]=(B)[(base)+1]; \
    _t[2]=(B)[(base)+2]; _t[3]=(B)[(base)+3]; (dst)=_t; }
#define FMA4(dst, a, W, base) { f4 _t=(dst); \
    _t[0]=fmaf((a),(W)[(base)+0],_t[0]); _t[1]=fmaf((a),(W)[(base)+1],_t[1]); \
    _t[2]=fmaf((a),(W)[(base)+2],_t[2]); _t[3]=fmaf((a),(W)[(base)+3],_t[3]); \
    (dst)=_t; }
#define RELU4(dst) { f4 _t=(dst); _t[0]=fmaxf(_t[0],0.f); _t[1]=fmaxf(_t[1],0.f); \
    _t[2]=fmaxf(_t[2],0.f); _t[3]=fmaxf(_t[3],0.f); (dst)=_t; }

// ---------------------------------------------------------------------------
// phi MLP (8->64 relu, 64->64 relu, 64->64) per row + sorted-segment wave
// suffix-scan + run-head atomics.
//
// Proven ingredients (R7/R8/R10 counter evidence):
//  - __launch_bounds__(256, 1): waves/EU=1 raises the PromoteAlloca VGPR
//    budget to 512 -> h arrays promote (R8: VGPR=188). At waves/EU=2 they
//    spill (R7: 68, R10: 80 VGPR; R10 FETCH=316MB scratch traffic).
//  - SCALAR float weight reads at wave-uniform compile-time indices ->
//    s_load + v_fmac(v,s,v) (R7/R10: SGPR=112). Vector-casting weights broke
//    this (R8: per-lane dwordx4 of the same addr, 4.7x slower).
//  - h state as f4[16], whole-vector load/store only; 2 arrays ping-ponged
//    (128 live regs) instead of 3 (192).
// ---------------------------------------------------------------------------
__global__ __launch_bounds__(256, 1) void phi_pool_kernel(
    const float* __restrict__ x,      // [TOTAL, 8]
    const int*   __restrict__ seg,    // [TOTAL] sorted
    const float* __restrict__ W1, const float* __restrict__ b1,   // [8,64],[64]
    const float* __restrict__ W2, const float* __restrict__ b2,   // [64,64],[64]
    const float* __restrict__ W3, const float* __restrict__ b3,   // [64,64],[64]
    float* __restrict__ pooled)       // [NSEG, 64] (pre-zeroed)
{
    const int r = blockIdx.x * 256 + threadIdx.x;

    // issue per-lane VMEM loads (segment id + row) before the FMA body
    const int s = seg[r];
    const f4* xp = reinterpret_cast<const f4*>(x + (size_t)r * 8);
    const f4 x0 = xp[0], x1 = xp[1];

    f4 hA[16], hB[16];   // ping-pong activation state

    // ---- layer 1: 8 -> 64 into hA, relu ----
#pragma unroll
    for (int j = 0; j < 16; ++j) INIT4(hA[j], b1, j * 4);
#pragma unroll
    for (int k = 0; k < 8; ++k) {
        const float a = (k < 4) ? x0[k] : x1[k - 4];   // k compile-time
#pragma unroll
        for (int j = 0; j < 16; ++j) FMA4(hA[j], a, W1, k * 64 + j * 4);
    }
#pragma unroll
    for (int j = 0; j < 16; ++j) RELU4(hA[j]);

    // ---- layer 2: 64 -> 64, hA -> hB, relu ----
#pragma unroll
    for (int j = 0; j < 16; ++j) INIT4(hB[j], b2, j * 4);
#pragma unroll
    for (int k = 0; k < 64; ++k) {
        const f4 av = hA[k >> 2];          // whole-vector load, const index
        const float a = av[k & 3];
#pragma unroll
        for (int j = 0; j < 16; ++j) FMA4(hB[j], a, W2, k * 64 + j * 4);
    }
#pragma unroll
    for (int j = 0; j < 16; ++j) RELU4(hB[j]);

    // ---- layer 3: 64 -> 64, hB -> hA (no relu) ----
#pragma unroll
    for (int j = 0; j < 16; ++j) INIT4(hA[j], b3, j * 4);
#pragma unroll
    for (int k = 0; k < 64; ++k) {
        const f4 av = hB[k >> 2];
        const float a = av[k & 3];
#pragma unroll
        for (int j = 0; j < 16; ++j) FMA4(hA[j], a, W3, k * 64 + j * 4);
    }

    // ---- wave-level segmented suffix sum over sorted ids ----
    const int lane = threadIdx.x & 63;

    bool ok0, ok1, ok2, ok3, ok4, ok5;
    {
        const int s1  = __shfl_down(s, 1);
        const int s2  = __shfl_down(s, 2);
        const int s4  = __shfl_down(s, 4);
        const int s8  = __shfl_down(s, 8);
        const int s16 = __shfl_down(s, 16);
        const int s32 = __shfl_down(s, 32);
        ok0 = (lane + 1  < 64) && (s1  == s);
        ok1 = (lane + 2  < 64) && (s2  == s);
        ok2 = (lane + 4  < 64) && (s4  == s);
        ok3 = (lane + 8  < 64) && (s8  == s);
        ok4 = (lane + 16 < 64) && (s16 == s);
        ok5 = (lane + 32 < 64) && (s32 == s);
    }
    const int  sprev = __shfl_up(s, 1);
    const bool head  = (lane == 0) || (sprev != s);
    float* p = pooled + (size_t)s * 64;

    // scan one f4 chunk at a time (whole-vector loads from hA)
#pragma unroll
    for (int j = 0; j < 16; ++j) {
        f4 v = hA[j];
#pragma unroll
        for (int t = 0; t < 6; ++t) {
            const int d = 1 << t;
            f4 o;
#pragma unroll
            for (int e = 0; e < 4; ++e) o[e] = __shfl_down(v[e], d);
            const bool ok = (t == 0) ? ok0 : (t == 1) ? ok1 : (t == 2) ? ok2
                          : (t == 3) ? ok3 : (t == 4) ? ok4 : ok5;
            if (ok) v += o;    // exec-masked add
        }
        if (head) {
#pragma unroll
            for (int e = 0; e < 4; ++e) atomicAdd(p + j * 4 + e, v[e]);
        }
    }
}

// ---------------------------------------------------------------------------
// rho MLP (64->64 relu, 64->64 relu, 64->4) per pooled row.
// 256 blocks x 64 threads -> covers all CUs. Same proven structure:
// (64,1) launch bounds, f4 ping-pong state, scalar uniform weight reads.
// ---------------------------------------------------------------------------
__global__ __launch_bounds__(64, 1) void rho_kernel(
    const float* __restrict__ pooled,  // [NSEG, 64]
    const float* __restrict__ W1, const float* __restrict__ b1,   // [64,64],[64]
    const float* __restrict__ W2, const float* __restrict__ b2,   // [64,64],[64]
    const float* __restrict__ W3, const float* __restrict__ b3,   // [64,4],[4]
    float* __restrict__ out)           // [NSEG, 4]
{
    const int r = blockIdx.x * 64 + threadIdx.x;

    f4 hA[16], hB[16];

    const f4* pp = reinterpret_cast<const f4*>(pooled + (size_t)r * 64);
#pragma unroll
    for (int j = 0; j < 16; ++j) hA[j] = pp[j];   // per-lane data: vector load OK

    // ---- layer 1: 64 -> 64, hA -> hB, relu ----
#pragma unroll
    for (int j = 0; j < 16; ++j) INIT4(hB[j], b1, j * 4);
#pragma unroll
    for (int k = 0; k < 64; ++k) {
        const f4 av = hA[k >> 2];
        const float a = av[k & 3];
#pragma unroll
        for (int j = 0; j < 16; ++j) FMA4(hB[j], a, W1, k * 64 + j * 4);
    }
#pragma unroll
    for (int j = 0; j < 16; ++j) RELU4(hB[j]);

    // ---- layer 2: 64 -> 64, hB -> hA, relu ----
#pragma unroll
    for (int j = 0; j < 16; ++j) INIT4(hA[j], b2, j * 4);
#pragma unroll
    for (int k = 0; k < 64; ++k) {
        const f4 av = hB[k >> 2];
        const float a = av[k & 3];
#pragma unroll
        for (int j = 0; j < 16; ++j) FMA4(hA[j], a, W2, k * 64 + j * 4);
    }
#pragma unroll
    for (int j = 0; j < 16; ++j) RELU4(hA[j]);

    // ---- layer 3: 64 -> 4 ----
    f4 o4;
    INIT4(o4, b3, 0);
#pragma unroll
    for (int k = 0; k < 64; ++k) {
        const f4 av = hA[k >> 2];
        const float a = av[k & 3];
        FMA4(o4, a, W3, k * 4);
    }

    f4* op = reinterpret_cast<f4*>(out + (size_t)r * 4);
    *op = o4;
}

extern "C" void kernel_launch(void* const* d_in, const int* in_sizes, int n_in,
                              void* d_out, int out_size, void* d_ws, size_t ws_size,
                              hipStream_t stream) {
    const float* neighbors = (const float*)d_in[0];
    const int*   seg       = (const int*)d_in[1];
    const float* phi_W1 = (const float*)d_in[2];
    const float* phi_b1 = (const float*)d_in[3];
    const float* phi_W2 = (const float*)d_in[4];
    const float* phi_b2 = (const float*)d_in[5];
    const float* phi_W3 = (const float*)d_in[6];
    const float* phi_b3 = (const float*)d_in[7];
    const float* rho_W1 = (const float*)d_in[8];
    const float* rho_b1 = (const float*)d_in[9];
    const float* rho_W2 = (const float*)d_in[10];
    const float* rho_b2 = (const float*)d_in[11];
    const float* rho_W3 = (const float*)d_in[12];
    const float* rho_b3 = (const float*)d_in[13];

    float* pooled = (float*)d_ws;                       // [NSEG, 64]
    float* outp   = (float*)d_out;                      // [NSEG, 4]

    // ws is re-poisoned to 0xAA before every launch -> must zero accumulator
    hipMemsetAsync(pooled, 0, (size_t)NSEG * 64 * sizeof(float), stream);

    phi_pool_kernel<<<TOTAL / 256, 256, 0, stream>>>(
        neighbors, seg, phi_W1, phi_b1, phi_W2, phi_b2, phi_W3, phi_b3, pooled);

    rho_kernel<<<NSEG / 64, 64, 0, stream>>>(
        pooled, rho_W1, rho_b1, rho_W2, rho_b2, rho_W3, rho_b3, outp);
}

// Round 16
// 369.543 us; speedup vs baseline: 3.8788x; 1.9957x over previous
//
#include <hip/hip_runtime.h>

#define TOTAL 524288
#define NSEG  16384

// ---------------------------------------------------------------------------
// phi MLP (8->64 relu, 64->64 relu, 64->64) per row + sorted-segment wave
// suffix-scan + run-head atomics.
//
// This is the R7 kernel body VERBATIM (its VALU-time was 76us, within 1.3x of
// the 59us pure-FMA floor -- the only round with a clean instruction mix),
// with ONE change: __launch_bounds__ min-waves/EU 2 -> 1. That doubles the
// PromoteAlloca VGPR budget to 512, which R8 proved sufficient to promote
// 192 floats of h-state (VGPR=188). R7's only defect was this failed
// promotion (VGPR=68, spill stalls, VALUBusy 27%).
//
// Weight reads stay SCALAR floats at wave-uniform compile-time indices
// (s_load + v_fmac v,s,v -- R7's clean 76us VALU-time is the evidence).
// Do NOT vector-cast weights (R8: 4.7x slower) and do NOT use elementwise
// f4 macros for h (R13: 6.5x VALU bloat).
// ---------------------------------------------------------------------------
__global__ __launch_bounds__(256, 1) void phi_pool_kernel(
    const float* __restrict__ x,      // [TOTAL, 8]
    const int*   __restrict__ seg,    // [TOTAL] sorted
    const float* __restrict__ W1, const float* __restrict__ b1,   // [8,64],[64]
    const float* __restrict__ W2, const float* __restrict__ b2,   // [64,64],[64]
    const float* __restrict__ W3, const float* __restrict__ b3,   // [64,64],[64]
    float* __restrict__ pooled)       // [NSEG, 64] (pre-zeroed)
{
    const int r = blockIdx.x * 256 + threadIdx.x;

    // issue both VMEM loads (row + segment id) before the long FMA body
    const int s = seg[r];

    float xr[8];
    const float4* xp = reinterpret_cast<const float4*>(x + (size_t)r * 8);
    float4 a0 = xp[0], a1 = xp[1];
    xr[0] = a0.x; xr[1] = a0.y; xr[2] = a0.z; xr[3] = a0.w;
    xr[4] = a1.x; xr[5] = a1.y; xr[6] = a1.z; xr[7] = a1.w;

    // ---- layer 1: 8 -> 64, relu ----
    float h1[64];
#pragma unroll
    for (int j = 0; j < 64; ++j) h1[j] = b1[j];
#pragma unroll
    for (int k = 0; k < 8; ++k) {
        const float a = xr[k];
#pragma unroll
        for (int j = 0; j < 64; ++j) h1[j] = fmaf(a, W1[k * 64 + j], h1[j]);
    }
#pragma unroll
    for (int j = 0; j < 64; ++j) h1[j] = fmaxf(h1[j], 0.0f);

    // ---- layer 2: 64 -> 64, relu ----
    float h2[64];
#pragma unroll
    for (int j = 0; j < 64; ++j) h2[j] = b2[j];
#pragma unroll
    for (int k = 0; k < 64; ++k) {
        const float a = h1[k];
#pragma unroll
        for (int j = 0; j < 64; ++j) h2[j] = fmaf(a, W2[k * 64 + j], h2[j]);
    }
#pragma unroll
    for (int j = 0; j < 64; ++j) h2[j] = fmaxf(h2[j], 0.0f);

    // ---- layer 3: 64 -> 64 (no relu) ----
    float h3[64];
#pragma unroll
    for (int j = 0; j < 64; ++j) h3[j] = b3[j];
#pragma unroll
    for (int k = 0; k < 64; ++k) {
        const float a = h2[k];
#pragma unroll
        for (int j = 0; j < 64; ++j) h3[j] = fmaf(a, W3[k * 64 + j], h3[j]);
    }

    // ---- wave-level segmented suffix sum over sorted ids ----
    // Invariant after stride d: lane i holds sum over [i, min(i+2d-1, run end)].
    const int lane = threadIdx.x & 63;

#pragma unroll
    for (int d = 1; d < 64; d <<= 1) {
        const int  sd = __shfl_down(s, d);
        const bool ok = (lane + d < 64) && (sd == s);
#pragma unroll
        for (int j = 0; j < 64; ++j) {
            const float o = __shfl_down(h3[j], d);  // all lanes participate
            if (ok) h3[j] += o;                     // exec-masked add
        }
    }

    // run head (first row of its segment within this wave) commits the run sum
    const int  sprev = __shfl_up(s, 1);
    const bool head  = (lane == 0) || (sprev != s);
    if (head) {
        float* p = pooled + (size_t)s * 64;
#pragma unroll
        for (int j = 0; j < 64; ++j) atomicAdd(p + j, h3[j]);
    }
}

// ---------------------------------------------------------------------------
// rho MLP (64->64 relu, 64->64 relu, 64->4) per pooled row.
// 256 blocks x 64 threads -> covers all CUs. Same (·,1) promotion budget.
// ---------------------------------------------------------------------------
__global__ __launch_bounds__(64, 1) void rho_kernel(
    const float* __restrict__ pooled,  // [NSEG, 64]
    const float* __restrict__ W1, const float* __restrict__ b1,   // [64,64],[64]
    const float* __restrict__ W2, const float* __restrict__ b2,   // [64,64],[64]
    const float* __restrict__ W3, const float* __restrict__ b3,   // [64,4],[4]
    float* __restrict__ out)           // [NSEG, 4]
{
    const int r = blockIdx.x * 64 + threadIdx.x;

    float h0[64];
    const float4* pp = reinterpret_cast<const float4*>(pooled + (size_t)r * 64);
#pragma unroll
    for (int q = 0; q < 16; ++q) {
        float4 v = pp[q];
        h0[4 * q + 0] = v.x; h0[4 * q + 1] = v.y;
        h0[4 * q + 2] = v.z; h0[4 * q + 3] = v.w;
    }

    float h1[64];
#pragma unroll
    for (int j = 0; j < 64; ++j) h1[j] = b1[j];
#pragma unroll
    for (int k = 0; k < 64; ++k) {
        const float a = h0[k];
#pragma unroll
        for (int j = 0; j < 64; ++j) h1[j] = fmaf(a, W1[k * 64 + j], h1[j]);
    }
#pragma unroll
    for (int j = 0; j < 64; ++j) h1[j] = fmaxf(h1[j], 0.0f);

    float h2[64];
#pragma unroll
    for (int j = 0; j < 64; ++j) h2[j] = b2[j];
#pragma unroll
    for (int k = 0; k < 64; ++k) {
        const float a = h1[k];
#pragma unroll
        for (int j = 0; j < 64; ++j) h2[j] = fmaf(a, W2[k * 64 + j], h2[j]);
    }
#pragma unroll
    for (int j = 0; j < 64; ++j) h2[j] = fmaxf(h2[j], 0.0f);

    float o4[4];
#pragma unroll
    for (int j = 0; j < 4; ++j) o4[j] = b3[j];
#pragma unroll
    for (int k = 0; k < 64; ++k) {
        const float a = h2[k];
#pragma unroll
        for (int j = 0; j < 4; ++j) o4[j] = fmaf(a, W3[k * 4 + j], o4[j]);
    }

    float4* op = reinterpret_cast<float4*>(out + (size_t)r * 4);
    *op = make_float4(o4[0], o4[1], o4[2], o4[3]);
}

extern "C" void kernel_launch(void* const* d_in, const int* in_sizes, int n_in,
                              void* d_out, int out_size, void* d_ws, size_t ws_size,
                              hipStream_t stream) {
    const float* neighbors = (const float*)d_in[0];
    const int*   seg       = (const int*)d_in[1];
    const float* phi_W1 = (const float*)d_in[2];
    const float* phi_b1 = (const float*)d_in[3];
    const float* phi_W2 = (const float*)d_in[4];
    const float* phi_b2 = (const float*)d_in[5];
    const float* phi_W3 = (const float*)d_in[6];
    const float* phi_b3 = (const float*)d_in[7];
    const float* rho_W1 = (const float*)d_in[8];
    const float* rho_b1 = (const float*)d_in[9];
    const float* rho_W2 = (const float*)d_in[10];
    const float* rho_b2 = (const float*)d_in[11];
    const float* rho_W3 = (const float*)d_in[12];
    const float* rho_b3 = (const float*)d_in[13];

    float* pooled = (float*)d_ws;                       // [NSEG, 64]
    float* outp   = (float*)d_out;                      // [NSEG, 4]

    // ws is re-poisoned to 0xAA before every launch -> must zero accumulator
    hipMemsetAsync(pooled, 0, (size_t)NSEG * 64 * sizeof(float), stream);

    phi_pool_kernel<<<TOTAL / 256, 256, 0, stream>>>(
        neighbors, seg, phi_W1, phi_b1, phi_W2, phi_b2, phi_W3, phi_b3, pooled);

    rho_kernel<<<NSEG / 64, 64, 0, stream>>>(
        pooled, rho_W1, rho_b1, rho_W2, rho_b2, rho_W3, rho_b3, outp);
}